// Round 10
// baseline (264.169 us; speedup 1.0000x reference)
//
#include <hip/hip_runtime.h>
#include <hip/hip_bf16.h>

#define B_ 2
#define S_ 2048
#define HID_ 1536
#define H_ 12
#define HD_ 128
#define LAT_ 192
#define ROT_ 64
#define M_ (B_*S_)         // 4096
#define NTILE_ (B_*H_*(S_/64))   // 768 attn q-tiles

// 1/sqrt(128) * log2(e): folded into Qf so attn softmax runs in log2 domain
#define SC2F 0.12752869f

typedef __hip_bfloat16 bf16;

using short8  = __attribute__((ext_vector_type(8))) short;
using short4v = __attribute__((ext_vector_type(4))) short;
using float4v = __attribute__((ext_vector_type(4))) float;

__device__ __forceinline__ unsigned short f2bf(float f) {
  __hip_bfloat16 h = __float2bfloat16(f);
  unsigned short u; __builtin_memcpy(&u, &h, 2); return u;
}

// async global->LDS, 16B per lane (wave-uniform LDS base + lane*16)
#define GLDS16(gp, lp) __builtin_amdgcn_global_load_lds( \
    (__attribute__((address_space(1))) void*)(size_t)(gp), \
    (__attribute__((address_space(3))) void*)(lp), 16, 0, 0)

__global__ __launch_bounds__(256)
void fillf_k(float* __restrict__ out, float v, int n)
{
  int i = blockIdx.x*256 + threadIdx.x;
  if (i < n) out[i] = v;
}

// ---------------------------------------------------------------------------
// Batched weight transpose+pack (z=0..3): W(K,N) fp32 -> Wt(N,K) bf16.
// (packA branch removed — hidden is now consumed fp32 directly by G1.)
// ---------------------------------------------------------------------------
__global__ __launch_bounds__(256)
void packT4_k(const float* __restrict__ s0, const float* __restrict__ s1,
              const float* __restrict__ s2, const float* __restrict__ s3,
              bf16* __restrict__ d0, bf16* __restrict__ d1,
              bf16* __restrict__ d2, bf16* __restrict__ d3,
              int Kn, int N0, int N1, int N2, int N3)
{
  const float* W; bf16* Wt; int Nn;
  switch (blockIdx.z) {
    case 0:  W = s0; Wt = d0; Nn = N0; break;
    case 1:  W = s1; Wt = d1; Nn = N1; break;
    case 2:  W = s2; Wt = d2; Nn = N2; break;
    default: W = s3; Wt = d3; Nn = N3; break;
  }
  const int kb = blockIdx.x*32, nb = blockIdx.y*32;
  if (nb >= Nn) return;
  __shared__ float t[32][33];
  const int tx = threadIdx.x & 31, ty = threadIdx.x >> 5;
  #pragma unroll
  for (int i = 0; i < 4; i++)
    t[ty+8*i][tx] = W[(size_t)(kb+ty+8*i)*Nn + nb + tx];
  __syncthreads();
  #pragma unroll
  for (int i = 0; i < 4; i++)
    Wt[(size_t)(nb + ty + 8*i)*Kn + kb + tx] = __float2bfloat16(t[tx][ty+8*i]);
}

// ---------------------------------------------------------------------------
// MFMA bf16 GEMM: C(M,N) = A(M,K) @ Bt(N,K)^T.  BM x BN tile, BK=64.
// BN=128: 4 waves 2x2 (wave = (BM/2)x64).  BN=64: 4 waves 4x1 (wave =
// (BM/4)x64) -- full-N waves keep rope pairs (j, j+2) lane-local and the
// doubled grid fills CUs (G1 576->1152, G4 768->1536 blocks) [R10].
// Single-buffered LDS (R8: dbuf halved blocks/CU, net negative).
// AF32=1: A read fp32 (hidden) with reg-staged cvt+swizzled ds_write (R4).
// LDS staged via global_load_lds with XOR-swizzled GLOBAL source (T2).
// CMODE epilogues (regions block-uniform; boundaries multiples of BN):
//   0: fp32 linear (ldc)                                 [out = at @ Wo]
//   5: c<384 -> dout bf16 (ldc 384); else ROPE -> Kf dims 64..127
//   6: c<768 -> Kf k_c head-split; <2304 -> V transposed -> Vtg;
//      <3072 -> Qf q_c head-split (*SC2F); else ROPE*SC2F -> Qf 64..127
//      (CMODE 6 selects A/B base by n0: >=2304 uses Av2/Bt2, rows n0-2304)
// Q is pre-scaled by SC2F so attention softmax needs no per-score multiply.
// ---------------------------------------------------------------------------
template<int CMODE, int BM, int BN, int AF32>
__global__ __launch_bounds__(256)
void gemm_mfma(const bf16* __restrict__ Av, const bf16* __restrict__ Btp,
               const bf16* __restrict__ Av2, const bf16* __restrict__ Bt2,
               void* __restrict__ Cv, void* __restrict__ Cv2,
               void* __restrict__ Cv3,
               const float* __restrict__ emb, int Kn, int lda, int ldb, int ldc)
{
  constexpr int WC   = (BN == 128) ? 2 : 1;        // wave cols
  constexpr int ROWS = (WC == 2) ? BM/2 : BM/4;    // rows per wave
  constexpr int MI   = ROWS/16;                    // 16-row tiles per wave
  constexpr int ITA  = BM/32;                      // A GLDS staging calls
  constexpr int ITB  = BN/32;                      // B GLDS staging calls
  __shared__ bf16 As[(size_t)BM*64];
  __shared__ bf16 Bs[(size_t)BN*64];

  const int tid  = threadIdx.x;
  const int lane = tid & 63;
  const int w    = tid >> 6;
  const int col  = lane & 15, quad = lane >> 4;
  const int wr   = (WC == 2) ? (w >> 1) : w;
  const int wc   = (WC == 2) ? (w & 1)  : 0;
  const size_t m0 = (size_t)blockIdx.y * BM;
  const size_t n0 = (size_t)blockIdx.x * BN;

  const bf16* Abase = Av;
  const bf16* Bt    = Btp;
  size_t nrow0 = n0;
  if constexpr (CMODE == 6) {
    if ((int)n0 >= 2304) { Abase = Av2; Bt = Bt2; nrow0 = n0 - 2304; }
  }

  const bf16* bg[ITB];
  #pragma unroll
  for (int it = 0; it < ITB; it++) {
    int c = tid + it*256, row = c >> 3, seg = c & 7;
    bg[it] = Bt + (nrow0 + row)*ldb + (size_t)((seg ^ (row & 7))*8);
  }
  const bf16* ag[ITA];
  const float* asrc = nullptr;
  int arow = 0;
  if constexpr (AF32) {
    arow = tid >> 2;
    const int aseg = tid & 3;
    asrc = (const float*)Av + (m0 + arow)*lda + aseg*16;
  } else {
    #pragma unroll
    for (int it = 0; it < ITA; it++) {
      int c = tid + it*256, row = c >> 3, seg = c & 7;
      ag[it] = Abase + (m0 + row)*lda + (size_t)((seg ^ (row & 7))*8);
    }
  }

  float4v acc[MI][4];
  #pragma unroll
  for (int i=0;i<MI;i++)
    #pragma unroll
    for (int j=0;j<4;j++) acc[i][j] = (float4v){0.f,0.f,0.f,0.f};

  for (int k0 = 0; k0 < Kn; k0 += 64) {
    #pragma unroll
    for (int it = 0; it < ITB; it++)
      GLDS16(bg[it] + k0, Bs + (size_t)(tid + it*256)*8);
    if constexpr (AF32) {
      const int aseg = tid & 3;
      float4 f0 = *(const float4*)(asrc + k0);
      float4 f1 = *(const float4*)(asrc + k0 + 4);
      float4 f2 = *(const float4*)(asrc + k0 + 8);
      float4 f3 = *(const float4*)(asrc + k0 + 12);
      short8 h0, h1;
      h0[0]=(short)f2bf(f0.x); h0[1]=(short)f2bf(f0.y);
      h0[2]=(short)f2bf(f0.z); h0[3]=(short)f2bf(f0.w);
      h0[4]=(short)f2bf(f1.x); h0[5]=(short)f2bf(f1.y);
      h0[6]=(short)f2bf(f1.z); h0[7]=(short)f2bf(f1.w);
      h1[0]=(short)f2bf(f2.x); h1[1]=(short)f2bf(f2.y);
      h1[2]=(short)f2bf(f2.z); h1[3]=(short)f2bf(f2.w);
      h1[4]=(short)f2bf(f3.x); h1[5]=(short)f2bf(f3.y);
      h1[6]=(short)f2bf(f3.z); h1[7]=(short)f2bf(f3.w);
      const int sl0 = (aseg*2) ^ (arow & 7), sl1 = (aseg*2+1) ^ (arow & 7);
      *(short8*)&As[arow*64 + sl0*8] = h0;
      *(short8*)&As[arow*64 + sl1*8] = h1;
    } else {
      #pragma unroll
      for (int it = 0; it < ITA; it++)
        GLDS16(ag[it] + k0, As + (size_t)(tid + it*256)*8);
    }
    __syncthreads();

    short8 af[MI][2], bfr[4][2];
    #pragma unroll
    for (int i=0;i<MI;i++) {
      const int ar = wr*ROWS + i*16 + col;
      #pragma unroll
      for (int k2=0;k2<2;k2++)
        af[i][k2] = *(const short8*)&As[ar*64 + ((k2*4+quad)^(ar&7))*8];
    }
    #pragma unroll
    for (int j=0;j<4;j++) {
      const int br = wc*64 + j*16 + col;
      #pragma unroll
      for (int k2=0;k2<2;k2++)
        bfr[j][k2] = *(const short8*)&Bs[br*64 + ((k2*4+quad)^(br&7))*8];
    }

    #pragma unroll
    for (int k2=0;k2<2;k2++)
      #pragma unroll
      for (int i=0;i<MI;i++)
        #pragma unroll
        for (int j=0;j<4;j++)
          acc[i][j] = __builtin_amdgcn_mfma_f32_16x16x32_bf16(af[i][k2], bfr[j][k2], acc[i][j], 0,0,0);
    __syncthreads();
  }

  // ---- epilogues ----
  if constexpr (CMODE == 0) {
    #pragma unroll
    for (int i=0;i<MI;i++) {
      const size_t row0 = m0 + wr*ROWS + i*16 + quad*4;
      #pragma unroll
      for (int j=0;j<4;j++) {
        const int c = (int)n0 + wc*64 + j*16 + col;
        #pragma unroll
        for (int r=0;r<4;r++)
          ((float*)Cv)[(row0+r)*ldc + c] = acc[i][j][r];
      }
    }
    return;
  }

  if constexpr (CMODE == 5) {
    if ((int)n0 < 384) {
      #pragma unroll
      for (int i=0;i<MI;i++) {
        const size_t row0 = m0 + wr*ROWS + i*16 + quad*4;
        #pragma unroll
        for (int j=0;j<4;j++) {
          const int c = (int)n0 + wc*64 + j*16 + col;
          #pragma unroll
          for (int r=0;r<4;r++)
            ((bf16*)Cv)[(row0+r)*384 + c] = __float2bfloat16(acc[i][j][r]);
        }
      }
    } else {
      // rope -> Kf dims 64..127 (unscaled); pair (j, j+2) is lane-local
      const int hh = (((int)n0 - 384) >> 6) + wc;
      #pragma unroll
      for (int i=0;i<MI;i++) {
        const size_t row0 = m0 + wr*ROWS + i*16 + quad*4;
        #pragma unroll
        for (int j=0;j<2;j++) {
          const int idim = j*16 + col;
          #pragma unroll
          for (int r=0;r<4;r++) {
            const size_t row = row0 + r;
            const int s = (int)(row & (S_-1));
            const float sn = emb[(size_t)s*ROT_ + idim];
            const float cs = emb[(size_t)s*ROT_ + 32 + idim];
            const float x1 = acc[i][j][r], x2 = acc[i][j+2][r];
            bf16* dst = (bf16*)Cv2 + (row*H_ + hh)*HD_ + 64 + idim;
            dst[0]  = __float2bfloat16(x1*cs - x2*sn);
            dst[32] = __float2bfloat16(x1*sn + x2*cs);
          }
        }
      }
    }
    return;
  }

  // CMODE == 6
  if ((int)n0 < 768) {
    // k_c head-split into Kf dims 0..63 (unscaled)
    #pragma unroll
    for (int i=0;i<MI;i++) {
      const size_t row0 = m0 + wr*ROWS + i*16 + quad*4;
      #pragma unroll
      for (int j=0;j<4;j++) {
        const int c = (int)n0 + wc*64 + j*16 + col;
        #pragma unroll
        for (int r=0;r<4;r++)
          ((bf16*)Cv)[(row0+r)*HID_ + (c>>6)*HD_ + (c&63)] = __float2bfloat16(acc[i][j][r]);
      }
    }
  } else if ((int)n0 < 2304) {
    // V transposed into Vtg[b][h][d][s]; 4 rows s-contiguous -> short4
    #pragma unroll
    for (int i=0;i<MI;i++) {
      const size_t row0 = m0 + wr*ROWS + i*16 + quad*4;
      const int bb = (int)(row0 >> 11), s = (int)(row0 & (S_-1));
      #pragma unroll
      for (int j=0;j<4;j++) {
        const int cv = (int)n0 - 768 + wc*64 + j*16 + col;
        const int hh = cv >> 7, d = cv & 127;
        short4v st;
        #pragma unroll
        for (int r=0;r<4;r++) st[r] = (short)f2bf(acc[i][j][r]);
        *(short4v*)((unsigned short*)Cv2 +
            ((size_t)(bb*H_+hh)*HD_ + d)*S_ + s) = st;
      }
    }
  } else if ((int)n0 < 3072) {
    // q_c head-split into Qf dims 0..63, PRE-SCALED by SC2F
    #pragma unroll
    for (int i=0;i<MI;i++) {
      const size_t row0 = m0 + wr*ROWS + i*16 + quad*4;
      #pragma unroll
      for (int j=0;j<4;j++) {
        const int c = (int)n0 - 2304 + wc*64 + j*16 + col;
        #pragma unroll
        for (int r=0;r<4;r++)
          ((bf16*)Cv3)[(row0+r)*HID_ + (c>>6)*HD_ + (c&63)] =
              __float2bfloat16(acc[i][j][r] * SC2F);
      }
    }
  } else {
    // rope -> Qf dims 64..127, PRE-SCALED by SC2F
    const int hh = (((int)n0 - 3072) >> 6) + wc;
    #pragma unroll
    for (int i=0;i<MI;i++) {
      const size_t row0 = m0 + wr*ROWS + i*16 + quad*4;
      #pragma unroll
      for (int j=0;j<2;j++) {
        const int idim = j*16 + col;
        #pragma unroll
        for (int r=0;r<4;r++) {
          const size_t row = row0 + r;
          const int s = (int)(row & (S_-1));
          const float sn = emb[(size_t)s*ROT_ + idim];
          const float cs = emb[(size_t)s*ROT_ + 32 + idim];
          const float x1 = acc[i][j][r], x2 = acc[i][j+2][r];
          bf16* dst = (bf16*)Cv3 + (row*H_ + hh)*HD_ + 64 + idim;
          dst[0]  = __float2bfloat16((x1*cs - x2*sn) * SC2F);
          dst[32] = __float2bfloat16((x1*sn + x2*cs) * SC2F);
        }
      }
    }
  }
}

// ---------------------------------------------------------------------------
// MFMA flash attention, causal. 4 waves = 64 queries/tile; 64-key blocks.
// R4 static qt-major long-first map (same-bh tiles 24 apart -> same XCD ->
// L2-resident K/V), LDS-staged K/V with T14 reg prefetch.
// VALU diet (R9, measured −7us): Q pre-scaled; native v_exp_f32; tree
// reductions.  Swapped QK^T, bulk/diag split, defer-max (T13), T5 setprio.
// ---------------------------------------------------------------------------
#define KSTR 136   // 128+8  (272B rows, 16B aligned)
#define VSTR 72    // 64+8   (144B rows, 16B aligned)
#define PSTR 72

__global__ __launch_bounds__(256)
void attn_mfma(const bf16* __restrict__ Qf, const bf16* __restrict__ Kf,
               const bf16* __restrict__ Vtg, bf16* __restrict__ at)
{
  const int rank = (int)blockIdx.x;
  const int qt = (S_/64 - 1) - rank/24;       // long-first, qt-major
  const int bh = rank % 24;
  const int h  = bh % H_, b = bh / H_;

  const int tid  = threadIdx.x;
  const int w    = tid >> 6;
  const int lane = tid & 63;
  const int col  = lane & 15;
  const int quad = lane >> 4;

  __shared__ unsigned short Ks[64*KSTR];       // 17408 B
  __shared__ unsigned short Vt[128*VSTR];      // 18432 B
  __shared__ unsigned short Ps[4][16*PSTR];    //  9216 B

  const int q0w = qt*64 + w*16;

  const unsigned short* Kb = (const unsigned short*)Kf +
      ((size_t)b*S_*H_ + h)*HD_;
  const unsigned short* Vb = (const unsigned short*)Vtg +
      (size_t)(b*H_ + h)*HD_*S_;

  const unsigned short* kgp[4]; unsigned short* kdst[4];
  const unsigned short* vgp[4]; unsigned short* vdst[4];
  #pragma unroll
  for (int it = 0; it < 4; it++) {
    int c = tid + it*256;
    int key = c >> 4, doff = (c & 15)*8;
    kgp[it]  = Kb + (size_t)key*HID_ + doff;
    kdst[it] = &Ks[key*KSTR + doff];
    int d = c >> 3, kg = (c & 7)*8;
    vgp[it]  = Vb + (size_t)d*S_ + kg;
    vdst[it] = &Vt[d*VSTR + kg];
  }

  // Q fragments (B-operand of swapped QK^T; pre-scaled by SC2F at pack)
  short8 qf[4];
  {
    const unsigned short* qrow = (const unsigned short*)Qf +
        ((size_t)((size_t)b*S_ + q0w + col)*H_ + h)*HD_;
    #pragma unroll
    for (int kk = 0; kk < 4; kk++)
      qf[kk] = *(const short8*)(qrow + kk*32 + quad*8);
  }

  float4v O[8];
  #pragma unroll
  for (int t=0;t<8;t++) O[t] = (float4v){0.f,0.f,0.f,0.f};
  float m_ln = -1e30f, l_ln = 0.f;

  short8 kr[4], vr[4];
  #pragma unroll
  for (int it = 0; it < 4; it++) {
    kr[it] = *(const short8*)kgp[it];
    vr[it] = *(const short8*)vgp[it];
  }

  for (int kb = 0; kb <= qt; kb++) {
    const int k0 = kb * 64;
    const bool diag = (kb == qt);

    #pragma unroll
    for (int it = 0; it < 4; it++) *(short8*)kdst[it] = kr[it];
    #pragma unroll
    for (int it = 0; it < 4; it++) *(short8*)vdst[it] = vr[it];
    __syncthreads();

    if (!diag) {   // T14 prefetch
      const size_t kn = (size_t)(k0 + 64);
      #pragma unroll
      for (int it = 0; it < 4; it++) {
        kr[it] = *(const short8*)(kgp[it] + kn*HID_);
        vr[it] = *(const short8*)(vgp[it] + kn);
      }
    }

    float4v Sf[4];
    #pragma unroll
    for (int tc=0;tc<4;tc++) Sf[tc] = (float4v){0.f,0.f,0.f,0.f};
    __builtin_amdgcn_s_setprio(1);
    if (!diag) {
      #pragma unroll
      for (int tc = 0; tc < 4; tc++)
        #pragma unroll
        for (int kk = 0; kk < 4; kk++) {
          short8 kfrag = *(const short8*)&Ks[(16*tc+col)*KSTR + 32*kk + quad*8];
          Sf[tc] = __builtin_amdgcn_mfma_f32_16x16x32_bf16(kfrag, qf[kk], Sf[tc], 0,0,0);
        }
    } else {
      #pragma unroll
      for (int tc = 0; tc < 4; tc++) {
        if (tc <= w) {
          #pragma unroll
          for (int kk = 0; kk < 4; kk++) {
            short8 kfrag = *(const short8*)&Ks[(16*tc+col)*KSTR + 32*kk + quad*8];
            Sf[tc] = __builtin_amdgcn_mfma_f32_16x16x32_bf16(kfrag, qf[kk], Sf[tc], 0,0,0);
          }
        }
      }
    }
    __builtin_amdgcn_s_setprio(0);

    // ---- softmax (log2 domain; scores already scaled via Qf) ----
    float sv[4][4];
    if (!diag) {
      #pragma unroll
      for (int tc = 0; tc < 4; tc++)
        #pragma unroll
        for (int r = 0; r < 4; r++)
          sv[tc][r] = Sf[tc][r];
    } else {
      const int qrel = w*16 + col;
      #pragma unroll
      for (int tc = 0; tc < 4; tc++)
        #pragma unroll
        for (int r = 0; r < 4; r++)
          sv[tc][r] = (tc*16 + quad*4 + r > qrel) ? -3.0e38f : Sf[tc][r];
    }
    // tree max (depth 4)
    float ma[4];
    #pragma unroll
    for (int tc = 0; tc < 4; tc++)
      ma[tc] = fmaxf(fmaxf(sv[tc][0], sv[tc][1]), fmaxf(sv[tc][2], sv[tc][3]));
    float pmax = fmaxf(fmaxf(ma[0], ma[1]), fmaxf(ma[2], ma[3]));
    pmax = fmaxf(pmax, __shfl_xor(pmax, 16));
    pmax = fmaxf(pmax, __shfl_xor(pmax, 32));

    if (__all(pmax <= m_ln + 11.0f)) {        // T13 defer-max: no rescale
      float sa[4];
      #pragma unroll
      for (int tc = 0; tc < 4; tc++) {
        #pragma unroll
        for (int r = 0; r < 4; r++)
          sv[tc][r] = __builtin_amdgcn_exp2f(sv[tc][r] - m_ln);
        sa[tc] = (sv[tc][0] + sv[tc][1]) + (sv[tc][2] + sv[tc][3]);
      }
      float lt = (sa[0] + sa[1]) + (sa[2] + sa[3]);
      lt += __shfl_xor(lt, 16);
      lt += __shfl_xor(lt, 32);
      l_ln += lt;
    } else {
      const float mnew = fmaxf(m_ln, pmax);
      float sa[4];
      #pragma unroll
      for (int tc = 0; tc < 4; tc++) {
        #pragma unroll
        for (int r = 0; r < 4; r++)
          sv[tc][r] = __builtin_amdgcn_exp2f(sv[tc][r] - mnew);
        sa[tc] = (sv[tc][0] + sv[tc][1]) + (sv[tc][2] + sv[tc][3]);
      }
      float lt = (sa[0] + sa[1]) + (sa[2] + sa[3]);
      lt += __shfl_xor(lt, 16);
      lt += __shfl_xor(lt, 32);
      const float al = __builtin_amdgcn_exp2f(m_ln - mnew);
      l_ln = l_ln * al + lt;
      m_ln = mnew;
      float alr[4];
      #pragma unroll
      for (int r = 0; r < 4; r++) alr[r] = __shfl(al, quad*4 + r);
      #pragma unroll
      for (int t = 0; t < 8; t++)
        #pragma unroll
        for (int r = 0; r < 4; r++) O[t][r] *= alr[r];
    }

    #pragma unroll
    for (int tc = 0; tc < 4; tc++) {
      short4v pw;
      pw[0] = (short)f2bf(sv[tc][0]); pw[1] = (short)f2bf(sv[tc][1]);
      pw[2] = (short)f2bf(sv[tc][2]); pw[3] = (short)f2bf(sv[tc][3]);
      *(short4v*)&Ps[w][col*PSTR + tc*16 + quad*4] = pw;
    }

    __builtin_amdgcn_s_setprio(1);
    if (!diag) {
      #pragma unroll
      for (int ks = 0; ks < 2; ks++) {
        short8 pf = *(const short8*)&Ps[w][col*PSTR + 32*ks + quad*8];
        #pragma unroll
        for (int t = 0; t < 8; t++) {
          short8 vf = *(const short8*)&Vt[(16*t + col)*VSTR + 32*ks + quad*8];
          O[t] = __builtin_amdgcn_mfma_f32_16x16x32_bf16(pf, vf, O[t], 0,0,0);
        }
      }
    } else {
      #pragma unroll
      for (int ks = 0; ks < 2; ks++) {
        if (ks == 0 || w >= 2) {
          short8 pf = *(const short8*)&Ps[w][col*PSTR + 32*ks + quad*8];
          #pragma unroll
          for (int t = 0; t < 8; t++) {
            short8 vf = *(const short8*)&Vt[(16*t + col)*VSTR + 32*ks + quad*8];
            O[t] = __builtin_amdgcn_mfma_f32_16x16x32_bf16(pf, vf, O[t], 0,0,0);
          }
        }
      }
    }
    __builtin_amdgcn_s_setprio(0);
    __syncthreads();
  }

  float lr[4];
  #pragma unroll
  for (int r = 0; r < 4; r++) lr[r] = __shfl(l_ln, quad*4 + r);
  #pragma unroll
  for (int r = 0; r < 4; r++) {
    const float linv = 1.f / lr[r];
    const size_t mq = (size_t)b*S_ + q0w + quad*4 + r;
    bf16* dst = at + mq*HID_ + h*HD_ + col;
    #pragma unroll
    for (int t = 0; t < 8; t++)
      dst[16*t] = __float2bfloat16(O[t][r] * linv);
  }
}

extern "C" void kernel_launch(void* const* d_in, const int* in_sizes, int n_in,
                              void* d_out, int out_size, void* d_ws, size_t ws_size,
                              hipStream_t stream)
{
  float* out = (float*)d_out;

  // Size guard tripwire.
  static const int sz_dict[10] = {6291456,131072,294912,294912,147456,
                                  147456,294912,1179648,147456,2359296};
  int bad = -1;
  if (n_in < 10) bad = 15;
  else {
    for (int i = 0; i < 10; i++)
      if (in_sizes[i] != sz_dict[i]) { bad = i; break; }
  }
  if (bad >= 0) {
    float v = 1.0e6f * (float)(1 + bad);
    if (bad < 10) v += (float)(in_sizes[bad] % 1000000);
    fillf_k<<<(out_size + 255)/256, 256, 0, stream>>>(out, v, out_size);
    return;
  }

  const float* hidden = (const float*)d_in[0];
  const float* emb    = (const float*)d_in[1];
  const float* Wkvd   = (const float*)d_in[2];
  const float* Wqd    = (const float*)d_in[3];
  const float* Wku    = (const float*)d_in[4];
  const float* Wqu    = (const float*)d_in[5];
  const float* Wvu    = (const float*)d_in[6];
  const float* Wrk    = (const float*)d_in[7];
  const float* Wrq    = (const float*)d_in[8];
  const float* Wo     = (const float*)d_in[9];

  // --- workspace carve (256B aligned each) ---
  char* wp = (char*)d_ws;
  size_t used = 0;
  auto alloc = [&](size_t bytes) -> void* {
    void* p = wp + used;
    used += (bytes + 255) & ~(size_t)255;
    return p;
  };
  bf16*  dout  = (bf16*)alloc((size_t)M_*384*2);         // [kvd|qd] (M,384)
  bf16*  Kf    = (bf16*)alloc((size_t)M_*HID_*2);        // [m][h][128] bf16
  bf16*  Qf    = (bf16*)alloc((size_t)M_*HID_*2);
  bf16*  Vtg   = (bf16*)alloc((size_t)B_*H_*HD_*S_*2);   // [b][h][d][s] bf16
  bf16*  at    = (bf16*)alloc((size_t)M_*HID_*2);
  bf16*  WdkrT = (bf16*)alloc((size_t)1152*HID_*2);      // [WkvdT;WqdT;WrkT]
  bf16*  WkvuT = (bf16*)alloc((size_t)2304*LAT_*2);      // [WkuT;WvuT]
  bf16*  WqurT = (bf16*)alloc((size_t)1536*LAT_*2);      // [WquT;WrqT]
  bf16*  WoT   = (bf16*)alloc((size_t)HID_*HID_*2);

  if (used > ws_size) {   // workspace tripwire
    fillf_k<<<(out_size + 255)/256, 256, 0, stream>>>(out, 5.0e7f, out_size);
    return;
  }

  // --- weight packs (2 launches) ---
  packT4_k<<<dim3(48,48,4), 256, 0, stream>>>(
      Wkvd, Wqd, Wrk, Wo,
      WdkrT, WdkrT + (size_t)192*HID_, WdkrT + (size_t)384*HID_, WoT,
      HID_, LAT_, LAT_, H_*ROT_, HID_);
  packT4_k<<<dim3(6,48,4), 256, 0, stream>>>(
      Wku, Wvu, Wqu, Wrq,
      WkvuT, WkvuT + (size_t)768*LAT_, WqurT, WqurT + (size_t)768*LAT_,
      LAT_, H_*ROT_, HID_, H_*ROT_, H_*ROT_);

  // --- fused MFMA GEMMs (single-buffered) ---
  // G1: hidden(fp32, AF32 reg-staged) @ [Wkvd;Wqd;Wrk]^T -> dout | rope-K
  //     BN=64 4x1 waves: grid 1152 blocks (was 576)
  gemm_mfma<5,64,64,1><<<dim3(18, M_/64), 256, 0, stream>>>(
      (const bf16*)hidden, WdkrT, nullptr, nullptr, dout, Kf, nullptr, emb,
      HID_, HID_, HID_, 0);
  // G23: [dout|qd] @ [Wku;Wvu | Wqu;Wrq]^T -> k_c->Kf, V->Vtg, q_c->Qf, ropeQ
  gemm_mfma<6,128,128,0><<<dim3(30, M_/128), 256, 0, stream>>>(
      dout, WkvuT, dout + 192, WqurT, Kf, Vtg, Qf, emb, LAT_, 384, LAT_, 0);

  // MFMA flash attention (R4 static qt-major long-first, LDS-staged)
  attn_mfma<<<NTILE_, 256, 0, stream>>>(Qf, Kf, Vtg, at);

  // G4: out = at @ Wo   BN=64 4x1 waves: grid 1536 blocks (was 768)
  gemm_mfma<0,64,64,0><<<dim3(24, M_/64), 256, 0, stream>>>(
      at, WoT, nullptr, nullptr, out, nullptr, nullptr, emb, HID_, HID_, HID_, HID_);
}

// Round 11
// 237.158 us; speedup vs baseline: 1.1139x; 1.1139x over previous
//
#include <hip/hip_runtime.h>
#include <hip/hip_bf16.h>

#define B_ 2
#define S_ 2048
#define HID_ 1536
#define H_ 12
#define HD_ 128
#define LAT_ 192
#define ROT_ 64
#define M_ (B_*S_)         // 4096
#define NTILE_ (B_*H_*(S_/64))   // 768 attn q-tiles

// 1/sqrt(128) * log2(e): folded into Qf so attn softmax runs in log2 domain
#define SC2F 0.12752869f

typedef __hip_bfloat16 bf16;

using short8  = __attribute__((ext_vector_type(8))) short;
using short4v = __attribute__((ext_vector_type(4))) short;
using float4v = __attribute__((ext_vector_type(4))) float;

__device__ __forceinline__ unsigned short f2bf(float f) {
  __hip_bfloat16 h = __float2bfloat16(f);
  unsigned short u; __builtin_memcpy(&u, &h, 2); return u;
}

// async global->LDS, 16B per lane (wave-uniform LDS base + lane*16)
#define GLDS16(gp, lp) __builtin_amdgcn_global_load_lds( \
    (__attribute__((address_space(1))) void*)(size_t)(gp), \
    (__attribute__((address_space(3))) void*)(lp), 16, 0, 0)

__global__ __launch_bounds__(256)
void fillf_k(float* __restrict__ out, float v, int n)
{
  int i = blockIdx.x*256 + threadIdx.x;
  if (i < n) out[i] = v;
}

// ---------------------------------------------------------------------------
// Single merged pack launch (R11): z=0..3 big-K weights (Kn=1536),
// z=4..7 small-K weights (Kn=192, early-exit kb>=Kn), z=8 packA (hidden
// fp32 -> bf16, grid-stride).  W(K,N) fp32 -> Wt(N,K) bf16 via 32x33 LDS.
// ---------------------------------------------------------------------------
__global__ __launch_bounds__(256)
void packT9_k(const float* __restrict__ s0, const float* __restrict__ s1,
              const float* __restrict__ s2, const float* __restrict__ s3,
              const float* __restrict__ s4, const float* __restrict__ s5,
              const float* __restrict__ s6, const float* __restrict__ s7,
              bf16* __restrict__ d0, bf16* __restrict__ d1,
              bf16* __restrict__ d2, bf16* __restrict__ d3,
              bf16* __restrict__ d4, bf16* __restrict__ d5,
              bf16* __restrict__ d6, bf16* __restrict__ d7,
              const float* __restrict__ hsrc, bf16* __restrict__ hdst)
{
  const int z = (int)blockIdx.z;
  if (z == 8) {                        // packA branch (grid-stride float4)
    const int nblk = gridDim.x * gridDim.y;
    const int flatb = blockIdx.y * gridDim.x + blockIdx.x;
    const float4* in4 = (const float4*)hsrc;
    for (int i = flatb*256 + threadIdx.x; i < M_*HID_/4; i += nblk*256) {
      float4 v = in4[i];
      short4v o;
      o[0] = (short)f2bf(v.x); o[1] = (short)f2bf(v.y);
      o[2] = (short)f2bf(v.z); o[3] = (short)f2bf(v.w);
      *(short4v*)&hdst[i*4] = o;
    }
    return;
  }
  const float* W; bf16* Wt; int Nn;
  switch (z) {
    case 0:  W = s0; Wt = d0; Nn = 192;  break;  // Wkvd
    case 1:  W = s1; Wt = d1; Nn = 192;  break;  // Wqd
    case 2:  W = s2; Wt = d2; Nn = 768;  break;  // Wrk
    case 3:  W = s3; Wt = d3; Nn = 1536; break;  // Wo
    case 4:  W = s4; Wt = d4; Nn = 768;  break;  // Wku
    case 5:  W = s5; Wt = d5; Nn = 1536; break;  // Wvu
    case 6:  W = s6; Wt = d6; Nn = 768;  break;  // Wqu
    default: W = s7; Wt = d7; Nn = 768;  break;  // Wrq
  }
  const int Kn = (z < 4) ? HID_ : LAT_;
  const int kb = blockIdx.x*32, nb = blockIdx.y*32;
  if (kb >= Kn || nb >= Nn) return;
  __shared__ float t[32][33];
  const int tx = threadIdx.x & 31, ty = threadIdx.x >> 5;
  #pragma unroll
  for (int i = 0; i < 4; i++)
    t[ty+8*i][tx] = W[(size_t)(kb+ty+8*i)*Nn + nb + tx];
  __syncthreads();
  #pragma unroll
  for (int i = 0; i < 4; i++)
    Wt[(size_t)(nb + ty + 8*i)*Kn + kb + tx] = __float2bfloat16(t[tx][ty+8*i]);
}

// ---------------------------------------------------------------------------
// MFMA bf16 GEMM: C(M,N) = A(M,K) @ Bt(N,K)^T.  BM x 128 tile, BK=64,
// 4 waves 2x2, each wave (BM/2)x64.  Single-buffered LDS (measured best:
// R8 dbuf and R10 BN=64/AF32 both regressed — dbuf halves blocks/CU;
// narrow-N doubles A panel re-reads).  LDS staged via global_load_lds
// with XOR-swizzled GLOBAL source (T2 both-sides rule).
// CMODE epilogues (regions block-uniform; boundaries on 128 multiples):
//   0: fp32 linear (ldc)                                 [out = at @ Wo]
//   5: c<384 -> dout bf16 (ldc 384); else ROPE -> Kf dims 64..127
//   6: c<768 -> Kf k_c head-split; <2304 -> V transposed -> Vtg;
//      <3072 -> Qf q_c head-split (*SC2F); else ROPE*SC2F -> Qf 64..127
//      (CMODE 6 selects A/B base by n0: >=2304 uses Av2/Bt2, rows n0-2304)
// Q is pre-scaled by SC2F so attention softmax needs no per-score multiply.
// ---------------------------------------------------------------------------
template<int CMODE, int BM>
__global__ __launch_bounds__(256)
void gemm_mfma(const bf16* __restrict__ Av, const bf16* __restrict__ Btp,
               const bf16* __restrict__ Av2, const bf16* __restrict__ Bt2,
               void* __restrict__ Cv, void* __restrict__ Cv2,
               void* __restrict__ Cv3,
               const float* __restrict__ emb, int Kn, int lda, int ldb, int ldc)
{
  constexpr int MI  = BM/32;         // 16-row tiles per wave
  constexpr int ITA = BM/32;         // A GLDS staging calls
  __shared__ bf16 As[(size_t)BM*64];
  __shared__ bf16 Bs[128*64];

  const int tid  = threadIdx.x;
  const int lane = tid & 63;
  const int w    = tid >> 6;
  const int col  = lane & 15, quad = lane >> 4;
  const int wr   = w >> 1, wc = w & 1;
  const size_t m0 = (size_t)blockIdx.y * BM;
  const size_t n0 = (size_t)blockIdx.x * 128;

  const bf16* Abase = Av;
  const bf16* Bt    = Btp;
  size_t nrow0 = n0;
  if constexpr (CMODE == 6) {
    if ((int)n0 >= 2304) { Abase = Av2; Bt = Bt2; nrow0 = n0 - 2304; }
  }

  const bf16* bg[4];
  #pragma unroll
  for (int it = 0; it < 4; it++) {
    int c = tid + it*256, row = c >> 3, seg = c & 7;
    bg[it] = Bt + (nrow0 + row)*ldb + (size_t)((seg ^ (row & 7))*8);
  }
  const bf16* ag[ITA];
  #pragma unroll
  for (int it = 0; it < ITA; it++) {
    int c = tid + it*256, row = c >> 3, seg = c & 7;
    ag[it] = Abase + (m0 + row)*lda + (size_t)((seg ^ (row & 7))*8);
  }

  float4v acc[MI][4];
  #pragma unroll
  for (int i=0;i<MI;i++)
    #pragma unroll
    for (int j=0;j<4;j++) acc[i][j] = (float4v){0.f,0.f,0.f,0.f};

  for (int k0 = 0; k0 < Kn; k0 += 64) {
    #pragma unroll
    for (int it = 0; it < 4; it++)
      GLDS16(bg[it] + k0, Bs + (size_t)(tid + it*256)*8);
    #pragma unroll
    for (int it = 0; it < ITA; it++)
      GLDS16(ag[it] + k0, As + (size_t)(tid + it*256)*8);
    __syncthreads();

    short8 af[MI][2], bfr[4][2];
    #pragma unroll
    for (int i=0;i<MI;i++) {
      const int ar = wr*(BM/2) + i*16 + col;
      #pragma unroll
      for (int k2=0;k2<2;k2++)
        af[i][k2] = *(const short8*)&As[ar*64 + ((k2*4+quad)^(ar&7))*8];
    }
    #pragma unroll
    for (int j=0;j<4;j++) {
      const int br = wc*64 + j*16 + col;
      #pragma unroll
      for (int k2=0;k2<2;k2++)
        bfr[j][k2] = *(const short8*)&Bs[br*64 + ((k2*4+quad)^(br&7))*8];
    }

    #pragma unroll
    for (int k2=0;k2<2;k2++)
      #pragma unroll
      for (int i=0;i<MI;i++)
        #pragma unroll
        for (int j=0;j<4;j++)
          acc[i][j] = __builtin_amdgcn_mfma_f32_16x16x32_bf16(af[i][k2], bfr[j][k2], acc[i][j], 0,0,0);
    __syncthreads();
  }

  // ---- epilogues ----
  if constexpr (CMODE == 0) {
    #pragma unroll
    for (int i=0;i<MI;i++) {
      const size_t row0 = m0 + wr*(BM/2) + i*16 + quad*4;
      #pragma unroll
      for (int j=0;j<4;j++) {
        const int c = (int)n0 + wc*64 + j*16 + col;
        #pragma unroll
        for (int r=0;r<4;r++)
          ((float*)Cv)[(row0+r)*ldc + c] = acc[i][j][r];
      }
    }
    return;
  }

  if constexpr (CMODE == 5) {
    if ((int)n0 < 384) {
      #pragma unroll
      for (int i=0;i<MI;i++) {
        const size_t row0 = m0 + wr*(BM/2) + i*16 + quad*4;
        #pragma unroll
        for (int j=0;j<4;j++) {
          const int c = (int)n0 + wc*64 + j*16 + col;
          #pragma unroll
          for (int r=0;r<4;r++)
            ((bf16*)Cv)[(row0+r)*384 + c] = __float2bfloat16(acc[i][j][r]);
        }
      }
    } else {
      // rope -> Kf dims 64..127 (unscaled); pair (j, j+2) is lane-local
      const int hh = (((int)n0 - 384) >> 6) + wc;
      #pragma unroll
      for (int i=0;i<MI;i++) {
        const size_t row0 = m0 + wr*(BM/2) + i*16 + quad*4;
        #pragma unroll
        for (int j=0;j<2;j++) {
          const int idim = j*16 + col;
          #pragma unroll
          for (int r=0;r<4;r++) {
            const size_t row = row0 + r;
            const int s = (int)(row & (S_-1));
            const float sn = emb[(size_t)s*ROT_ + idim];
            const float cs = emb[(size_t)s*ROT_ + 32 + idim];
            const float x1 = acc[i][j][r], x2 = acc[i][j+2][r];
            bf16* dst = (bf16*)Cv2 + (row*H_ + hh)*HD_ + 64 + idim;
            dst[0]  = __float2bfloat16(x1*cs - x2*sn);
            dst[32] = __float2bfloat16(x1*sn + x2*cs);
          }
        }
      }
    }
    return;
  }

  // CMODE == 6
  if ((int)n0 < 768) {
    // k_c head-split into Kf dims 0..63 (unscaled)
    #pragma unroll
    for (int i=0;i<MI;i++) {
      const size_t row0 = m0 + wr*(BM/2) + i*16 + quad*4;
      #pragma unroll
      for (int j=0;j<4;j++) {
        const int c = (int)n0 + wc*64 + j*16 + col;
        #pragma unroll
        for (int r=0;r<4;r++)
          ((bf16*)Cv)[(row0+r)*HID_ + (c>>6)*HD_ + (c&63)] = __float2bfloat16(acc[i][j][r]);
      }
    }
  } else if ((int)n0 < 2304) {
    // V transposed into Vtg[b][h][d][s]; 4 rows s-contiguous -> short4
    #pragma unroll
    for (int i=0;i<MI;i++) {
      const size_t row0 = m0 + wr*(BM/2) + i*16 + quad*4;
      const int bb = (int)(row0 >> 11), s = (int)(row0 & (S_-1));
      #pragma unroll
      for (int j=0;j<4;j++) {
        const int cv = (int)n0 - 768 + wc*64 + j*16 + col;
        const int hh = cv >> 7, d = cv & 127;
        short4v st;
        #pragma unroll
        for (int r=0;r<4;r++) st[r] = (short)f2bf(acc[i][j][r]);
        *(short4v*)((unsigned short*)Cv2 +
            ((size_t)(bb*H_+hh)*HD_ + d)*S_ + s) = st;
      }
    }
  } else if ((int)n0 < 3072) {
    // q_c head-split into Qf dims 0..63, PRE-SCALED by SC2F
    #pragma unroll
    for (int i=0;i<MI;i++) {
      const size_t row0 = m0 + wr*(BM/2) + i*16 + quad*4;
      #pragma unroll
      for (int j=0;j<4;j++) {
        const int c = (int)n0 - 2304 + wc*64 + j*16 + col;
        #pragma unroll
        for (int r=0;r<4;r++)
          ((bf16*)Cv3)[(row0+r)*HID_ + (c>>6)*HD_ + (c&63)] =
              __float2bfloat16(acc[i][j][r] * SC2F);
      }
    }
  } else {
    // rope -> Qf dims 64..127, PRE-SCALED by SC2F
    const int hh = (((int)n0 - 3072) >> 6) + wc;
    #pragma unroll
    for (int i=0;i<MI;i++) {
      const size_t row0 = m0 + wr*(BM/2) + i*16 + quad*4;
      #pragma unroll
      for (int j=0;j<2;j++) {
        const int idim = j*16 + col;
        #pragma unroll
        for (int r=0;r<4;r++) {
          const size_t row = row0 + r;
          const int s = (int)(row & (S_-1));
          const float sn = emb[(size_t)s*ROT_ + idim];
          const float cs = emb[(size_t)s*ROT_ + 32 + idim];
          const float x1 = acc[i][j][r], x2 = acc[i][j+2][r];
          bf16* dst = (bf16*)Cv3 + (row*H_ + hh)*HD_ + 64 + idim;
          dst[0]  = __float2bfloat16((x1*cs - x2*sn) * SC2F);
          dst[32] = __float2bfloat16((x1*sn + x2*cs) * SC2F);
        }
      }
    }
  }
}

// ---------------------------------------------------------------------------
// MFMA flash attention, causal. 4 waves = 64 queries/tile; 64-key blocks.
// R4 static qt-major long-first map (same-bh tiles 24 apart -> same XCD ->
// L2-resident K/V), LDS-staged K/V with T14 reg prefetch.
// VALU diet (R9, measured −7us): Q pre-scaled; native v_exp_f32; tree
// reductions.  Swapped QK^T, bulk/diag split, defer-max (T13), T5 setprio.
// ---------------------------------------------------------------------------
#define KSTR 136   // 128+8  (272B rows, 16B aligned)
#define VSTR 72    // 64+8   (144B rows, 16B aligned)
#define PSTR 72

__global__ __launch_bounds__(256)
void attn_mfma(const bf16* __restrict__ Qf, const bf16* __restrict__ Kf,
               const bf16* __restrict__ Vtg, bf16* __restrict__ at)
{
  const int rank = (int)blockIdx.x;
  const int qt = (S_/64 - 1) - rank/24;       // long-first, qt-major
  const int bh = rank % 24;
  const int h  = bh % H_, b = bh / H_;

  const int tid  = threadIdx.x;
  const int w    = tid >> 6;
  const int lane = tid & 63;
  const int col  = lane & 15;
  const int quad = lane >> 4;

  __shared__ unsigned short Ks[64*KSTR];       // 17408 B
  __shared__ unsigned short Vt[128*VSTR];      // 18432 B
  __shared__ unsigned short Ps[4][16*PSTR];    //  9216 B

  const int q0w = qt*64 + w*16;

  const unsigned short* Kb = (const unsigned short*)Kf +
      ((size_t)b*S_*H_ + h)*HD_;
  const unsigned short* Vb = (const unsigned short*)Vtg +
      (size_t)(b*H_ + h)*HD_*S_;

  const unsigned short* kgp[4]; unsigned short* kdst[4];
  const unsigned short* vgp[4]; unsigned short* vdst[4];
  #pragma unroll
  for (int it = 0; it < 4; it++) {
    int c = tid + it*256;
    int key = c >> 4, doff = (c & 15)*8;
    kgp[it]  = Kb + (size_t)key*HID_ + doff;
    kdst[it] = &Ks[key*KSTR + doff];
    int d = c >> 3, kg = (c & 7)*8;
    vgp[it]  = Vb + (size_t)d*S_ + kg;
    vdst[it] = &Vt[d*VSTR + kg];
  }

  // Q fragments (B-operand of swapped QK^T; pre-scaled by SC2F at pack)
  short8 qf[4];
  {
    const unsigned short* qrow = (const unsigned short*)Qf +
        ((size_t)((size_t)b*S_ + q0w + col)*H_ + h)*HD_;
    #pragma unroll
    for (int kk = 0; kk < 4; kk++)
      qf[kk] = *(const short8*)(qrow + kk*32 + quad*8);
  }

  float4v O[8];
  #pragma unroll
  for (int t=0;t<8;t++) O[t] = (float4v){0.f,0.f,0.f,0.f};
  float m_ln = -1e30f, l_ln = 0.f;

  short8 kr[4], vr[4];
  #pragma unroll
  for (int it = 0; it < 4; it++) {
    kr[it] = *(const short8*)kgp[it];
    vr[it] = *(const short8*)vgp[it];
  }

  for (int kb = 0; kb <= qt; kb++) {
    const int k0 = kb * 64;
    const bool diag = (kb == qt);

    #pragma unroll
    for (int it = 0; it < 4; it++) *(short8*)kdst[it] = kr[it];
    #pragma unroll
    for (int it = 0; it < 4; it++) *(short8*)vdst[it] = vr[it];
    __syncthreads();

    if (!diag) {   // T14 prefetch
      const size_t kn = (size_t)(k0 + 64);
      #pragma unroll
      for (int it = 0; it < 4; it++) {
        kr[it] = *(const short8*)(kgp[it] + kn*HID_);
        vr[it] = *(const short8*)(vgp[it] + kn);
      }
    }

    float4v Sf[4];
    #pragma unroll
    for (int tc=0;tc<4;tc++) Sf[tc] = (float4v){0.f,0.f,0.f,0.f};
    __builtin_amdgcn_s_setprio(1);
    if (!diag) {
      #pragma unroll
      for (int tc = 0; tc < 4; tc++)
        #pragma unroll
        for (int kk = 0; kk < 4; kk++) {
          short8 kfrag = *(const short8*)&Ks[(16*tc+col)*KSTR + 32*kk + quad*8];
          Sf[tc] = __builtin_amdgcn_mfma_f32_16x16x32_bf16(kfrag, qf[kk], Sf[tc], 0,0,0);
        }
    } else {
      #pragma unroll
      for (int tc = 0; tc < 4; tc++) {
        if (tc <= w) {
          #pragma unroll
          for (int kk = 0; kk < 4; kk++) {
            short8 kfrag = *(const short8*)&Ks[(16*tc+col)*KSTR + 32*kk + quad*8];
            Sf[tc] = __builtin_amdgcn_mfma_f32_16x16x32_bf16(kfrag, qf[kk], Sf[tc], 0,0,0);
          }
        }
      }
    }
    __builtin_amdgcn_s_setprio(0);

    // ---- softmax (log2 domain; scores already scaled via Qf) ----
    float sv[4][4];
    if (!diag) {
      #pragma unroll
      for (int tc = 0; tc < 4; tc++)
        #pragma unroll
        for (int r = 0; r < 4; r++)
          sv[tc][r] = Sf[tc][r];
    } else {
      const int qrel = w*16 + col;
      #pragma unroll
      for (int tc = 0; tc < 4; tc++)
        #pragma unroll
        for (int r = 0; r < 4; r++)
          sv[tc][r] = (tc*16 + quad*4 + r > qrel) ? -3.0e38f : Sf[tc][r];
    }
    // tree max (depth 4)
    float ma[4];
    #pragma unroll
    for (int tc = 0; tc < 4; tc++)
      ma[tc] = fmaxf(fmaxf(sv[tc][0], sv[tc][1]), fmaxf(sv[tc][2], sv[tc][3]));
    float pmax = fmaxf(fmaxf(ma[0], ma[1]), fmaxf(ma[2], ma[3]));
    pmax = fmaxf(pmax, __shfl_xor(pmax, 16));
    pmax = fmaxf(pmax, __shfl_xor(pmax, 32));

    if (__all(pmax <= m_ln + 11.0f)) {        // T13 defer-max: no rescale
      float sa[4];
      #pragma unroll
      for (int tc = 0; tc < 4; tc++) {
        #pragma unroll
        for (int r = 0; r < 4; r++)
          sv[tc][r] = __builtin_amdgcn_exp2f(sv[tc][r] - m_ln);
        sa[tc] = (sv[tc][0] + sv[tc][1]) + (sv[tc][2] + sv[tc][3]);
      }
      float lt = (sa[0] + sa[1]) + (sa[2] + sa[3]);
      lt += __shfl_xor(lt, 16);
      lt += __shfl_xor(lt, 32);
      l_ln += lt;
    } else {
      const float mnew = fmaxf(m_ln, pmax);
      float sa[4];
      #pragma unroll
      for (int tc = 0; tc < 4; tc++) {
        #pragma unroll
        for (int r = 0; r < 4; r++)
          sv[tc][r] = __builtin_amdgcn_exp2f(sv[tc][r] - mnew);
        sa[tc] = (sv[tc][0] + sv[tc][1]) + (sv[tc][2] + sv[tc][3]);
      }
      float lt = (sa[0] + sa[1]) + (sa[2] + sa[3]);
      lt += __shfl_xor(lt, 16);
      lt += __shfl_xor(lt, 32);
      const float al = __builtin_amdgcn_exp2f(m_ln - mnew);
      l_ln = l_ln * al + lt;
      m_ln = mnew;
      float alr[4];
      #pragma unroll
      for (int r = 0; r < 4; r++) alr[r] = __shfl(al, quad*4 + r);
      #pragma unroll
      for (int t = 0; t < 8; t++)
        #pragma unroll
        for (int r = 0; r < 4; r++) O[t][r] *= alr[r];
    }

    #pragma unroll
    for (int tc = 0; tc < 4; tc++) {
      short4v pw;
      pw[0] = (short)f2bf(sv[tc][0]); pw[1] = (short)f2bf(sv[tc][1]);
      pw[2] = (short)f2bf(sv[tc][2]); pw[3] = (short)f2bf(sv[tc][3]);
      *(short4v*)&Ps[w][col*PSTR + tc*16 + quad*4] = pw;
    }

    __builtin_amdgcn_s_setprio(1);
    if (!diag) {
      #pragma unroll
      for (int ks = 0; ks < 2; ks++) {
        short8 pf = *(const short8*)&Ps[w][col*PSTR + 32*ks + quad*8];
        #pragma unroll
        for (int t = 0; t < 8; t++) {
          short8 vf = *(const short8*)&Vt[(16*t + col)*VSTR + 32*ks + quad*8];
          O[t] = __builtin_amdgcn_mfma_f32_16x16x32_bf16(pf, vf, O[t], 0,0,0);
        }
      }
    } else {
      #pragma unroll
      for (int ks = 0; ks < 2; ks++) {
        if (ks == 0 || w >= 2) {
          short8 pf = *(const short8*)&Ps[w][col*PSTR + 32*ks + quad*8];
          #pragma unroll
          for (int t = 0; t < 8; t++) {
            short8 vf = *(const short8*)&Vt[(16*t + col)*VSTR + 32*ks + quad*8];
            O[t] = __builtin_amdgcn_mfma_f32_16x16x32_bf16(pf, vf, O[t], 0,0,0);
          }
        }
      }
    }
    __builtin_amdgcn_s_setprio(0);
    __syncthreads();
  }

  float lr[4];
  #pragma unroll
  for (int r = 0; r < 4; r++) lr[r] = __shfl(l_ln, quad*4 + r);
  #pragma unroll
  for (int r = 0; r < 4; r++) {
    const float linv = 1.f / lr[r];
    const size_t mq = (size_t)b*S_ + q0w + quad*4 + r;
    bf16* dst = at + mq*HID_ + h*HD_ + col;
    #pragma unroll
    for (int t = 0; t < 8; t++)
      dst[16*t] = __float2bfloat16(O[t][r] * linv);
  }
}

extern "C" void kernel_launch(void* const* d_in, const int* in_sizes, int n_in,
                              void* d_out, int out_size, void* d_ws, size_t ws_size,
                              hipStream_t stream)
{
  float* out = (float*)d_out;

  // Size guard tripwire.
  static const int sz_dict[10] = {6291456,131072,294912,294912,147456,
                                  147456,294912,1179648,147456,2359296};
  int bad = -1;
  if (n_in < 10) bad = 15;
  else {
    for (int i = 0; i < 10; i++)
      if (in_sizes[i] != sz_dict[i]) { bad = i; break; }
  }
  if (bad >= 0) {
    float v = 1.0e6f * (float)(1 + bad);
    if (bad < 10) v += (float)(in_sizes[bad] % 1000000);
    fillf_k<<<(out_size + 255)/256, 256, 0, stream>>>(out, v, out_size);
    return;
  }

  const float* hidden = (const float*)d_in[0];
  const float* emb    = (const float*)d_in[1];
  const float* Wkvd   = (const float*)d_in[2];
  const float* Wqd    = (const float*)d_in[3];
  const float* Wku    = (const float*)d_in[4];
  const float* Wqu    = (const float*)d_in[5];
  const float* Wvu    = (const float*)d_in[6];
  const float* Wrk    = (const float*)d_in[7];
  const float* Wrq    = (const float*)d_in[8];
  const float* Wo     = (const float*)d_in[9];

  // --- workspace carve (256B aligned each) ---
  char* wp = (char*)d_ws;
  size_t used = 0;
  auto alloc = [&](size_t bytes) -> void* {
    void* p = wp + used;
    used += (bytes + 255) & ~(size_t)255;
    return p;
  };
  bf16*  hb    = (bf16*)alloc((size_t)M_*HID_*2);        // hidden bf16
  bf16*  dout  = (bf16*)alloc((size_t)M_*384*2);         // [kvd|qd] (M,384)
  bf16*  Kf    = (bf16*)alloc((size_t)M_*HID_*2);        // [m][h][128] bf16
  bf16*  Qf    = (bf16*)alloc((size_t)M_*HID_*2);
  bf16*  Vtg   = (bf16*)alloc((size_t)B_*H_*HD_*S_*2);   // [b][h][d][s] bf16
  bf16*  at    = (bf16*)alloc((size_t)M_*HID_*2);
  bf16*  WdkrT = (bf16*)alloc((size_t)1152*HID_*2);      // [WkvdT;WqdT;WrkT]
  bf16*  WkvuT = (bf16*)alloc((size_t)2304*LAT_*2);      // [WkuT;WvuT]
  bf16*  WqurT = (bf16*)alloc((size_t)1536*LAT_*2);      // [WquT;WrqT]
  bf16*  WoT   = (bf16*)alloc((size_t)HID_*HID_*2);

  if (used > ws_size) {   // workspace tripwire
    fillf_k<<<(out_size + 255)/256, 256, 0, stream>>>(out, 5.0e7f, out_size);
    return;
  }

  // --- merged weight packs + packA: ONE launch (R11) ---
  packT9_k<<<dim3(48,48,9), 256, 0, stream>>>(
      Wkvd, Wqd, Wrk, Wo, Wku, Wvu, Wqu, Wrq,
      WdkrT, WdkrT + (size_t)192*HID_, WdkrT + (size_t)384*HID_, WoT,
      WkvuT, WkvuT + (size_t)768*LAT_, WqurT, WqurT + (size_t)768*LAT_,
      hidden, hb);

  // --- fused MFMA GEMMs (single-buffered, R9 config) ---
  // G1: hb @ [Wkvd;Wqd;Wrk]^T -> dout | rope-K into Kf[64..127]  (576 blocks)
  gemm_mfma<5,64><<<dim3(9, M_/64), 256, 0, stream>>>(
      hb, WdkrT, nullptr, nullptr, dout, Kf, nullptr, emb, HID_, HID_, HID_, 0);
  // G23: [dout|qd] @ [Wku;Wvu | Wqu;Wrq]^T -> k_c->Kf, V->Vtg, q_c->Qf, ropeQ
  gemm_mfma<6,128><<<dim3(30, M_/128), 256, 0, stream>>>(
      dout, WkvuT, dout + 192, WqurT, Kf, Vtg, Qf, emb, LAT_, 384, LAT_, 0);

  // MFMA flash attention (R4 static qt-major long-first, LDS-staged)
  attn_mfma<<<NTILE_, 256, 0, stream>>>(Qf, Kf, Vtg, at);

  // G4: out = at @ Wo   (BM=64: 768 blocks for full CU coverage)
  gemm_mfma<0,64><<<dim3(12, M_/64), 256, 0, stream>>>(
      at, WoT, nullptr, nullptr, out, nullptr, nullptr, emb, HID_, HID_, HID_, HID_);
}

// Round 12
// 231.197 us; speedup vs baseline: 1.1426x; 1.0258x over previous
//
#include <hip/hip_runtime.h>
#include <hip/hip_bf16.h>

#define B_ 2
#define S_ 2048
#define HID_ 1536
#define H_ 12
#define HD_ 128
#define LAT_ 192
#define ROT_ 64
#define M_ (B_*S_)         // 4096
#define NTILE_ (B_*H_*(S_/64))   // 768 attn q-tiles

// 1/sqrt(128) * log2(e): folded into Qf so attn softmax runs in log2 domain
#define SC2F 0.12752869f

typedef __hip_bfloat16 bf16;

using short8  = __attribute__((ext_vector_type(8))) short;
using short4v = __attribute__((ext_vector_type(4))) short;
using float4v = __attribute__((ext_vector_type(4))) float;

__device__ __forceinline__ unsigned short f2bf(float f) {
  __hip_bfloat16 h = __float2bfloat16(f);
  unsigned short u; __builtin_memcpy(&u, &h, 2); return u;
}

// async global->LDS, 16B per lane (wave-uniform LDS base + lane*16)
#define GLDS16(gp, lp) __builtin_amdgcn_global_load_lds( \
    (__attribute__((address_space(1))) void*)(size_t)(gp), \
    (__attribute__((address_space(3))) void*)(lp), 16, 0, 0)

__global__ __launch_bounds__(256)
void fillf_k(float* __restrict__ out, float v, int n)
{
  int i = blockIdx.x*256 + threadIdx.x;
  if (i < n) out[i] = v;
}

// ---------------------------------------------------------------------------
// Single merged pack launch: z=0..3 big-K weights (Kn=1536), z=4..7
// small-K weights (Kn=192, early-exit kb>=Kn), z=8 packA (hidden fp32 ->
// bf16, grid-stride).  W(K,N) fp32 -> Wt(N,K) bf16 via 32x33 LDS tile.
// ---------------------------------------------------------------------------
__global__ __launch_bounds__(256)
void packT9_k(const float* __restrict__ s0, const float* __restrict__ s1,
              const float* __restrict__ s2, const float* __restrict__ s3,
              const float* __restrict__ s4, const float* __restrict__ s5,
              const float* __restrict__ s6, const float* __restrict__ s7,
              bf16* __restrict__ d0, bf16* __restrict__ d1,
              bf16* __restrict__ d2, bf16* __restrict__ d3,
              bf16* __restrict__ d4, bf16* __restrict__ d5,
              bf16* __restrict__ d6, bf16* __restrict__ d7,
              const float* __restrict__ hsrc, bf16* __restrict__ hdst)
{
  const int z = (int)blockIdx.z;
  if (z == 8) {                        // packA branch (grid-stride float4)
    const int nblk = gridDim.x * gridDim.y;
    const int flatb = blockIdx.y * gridDim.x + blockIdx.x;
    const float4* in4 = (const float4*)hsrc;
    for (int i = flatb*256 + threadIdx.x; i < M_*HID_/4; i += nblk*256) {
      float4 v = in4[i];
      short4v o;
      o[0] = (short)f2bf(v.x); o[1] = (short)f2bf(v.y);
      o[2] = (short)f2bf(v.z); o[3] = (short)f2bf(v.w);
      *(short4v*)&hdst[i*4] = o;
    }
    return;
  }
  const float* W; bf16* Wt; int Nn;
  switch (z) {
    case 0:  W = s0; Wt = d0; Nn = 192;  break;  // Wkvd
    case 1:  W = s1; Wt = d1; Nn = 192;  break;  // Wqd
    case 2:  W = s2; Wt = d2; Nn = 768;  break;  // Wrk
    case 3:  W = s3; Wt = d3; Nn = 1536; break;  // Wo
    case 4:  W = s4; Wt = d4; Nn = 768;  break;  // Wku
    case 5:  W = s5; Wt = d5; Nn = 1536; break;  // Wvu
    case 6:  W = s6; Wt = d6; Nn = 768;  break;  // Wqu
    default: W = s7; Wt = d7; Nn = 768;  break;  // Wrq
  }
  const int Kn = (z < 4) ? HID_ : LAT_;
  const int kb = blockIdx.x*32, nb = blockIdx.y*32;
  if (kb >= Kn || nb >= Nn) return;
  __shared__ float t[32][33];
  const int tx = threadIdx.x & 31, ty = threadIdx.x >> 5;
  #pragma unroll
  for (int i = 0; i < 4; i++)
    t[ty+8*i][tx] = W[(size_t)(kb+ty+8*i)*Nn + nb + tx];
  __syncthreads();
  #pragma unroll
  for (int i = 0; i < 4; i++)
    Wt[(size_t)(nb + ty + 8*i)*Kn + kb + tx] = __float2bfloat16(t[tx][ty+8*i]);
}

// ---------------------------------------------------------------------------
// MFMA bf16 GEMM: C(M,N) = A(M,K) @ Bt(N,K)^T.  BM x 128 tile, BK=64,
// 4 waves 2x2, each wave (BM/2)x64.  Single-buffered LDS (measured best:
// R8 dbuf and R10 BN=64/AF32 both regressed).  LDS staged via
// global_load_lds with XOR-swizzled GLOBAL source (T2 both-sides rule).
// R12: G23 runs BM=64 — its A/B panels (3 MB / 1.5 MB) are XCD-L2-resident
// so the extra A re-reads are L2-hits, and 1920 blocks @24.5 KB LDS give
// ~6 blocks/CU to hide the short-K (3-step) staging latency.
// CMODE epilogues (regions block-uniform; boundaries on 128 multiples):
//   0: fp32 linear (ldc)                                 [out = at @ Wo]
//   5: c<384 -> dout bf16 (ldc 384); else ROPE -> Kf dims 64..127
//   6: c<768 -> Kf k_c head-split; <2304 -> V transposed -> Vtg;
//      <3072 -> Qf q_c head-split (*SC2F); else ROPE*SC2F -> Qf 64..127
//      (CMODE 6 selects A/B base by n0: >=2304 uses Av2/Bt2, rows n0-2304)
// Q is pre-scaled by SC2F so attention softmax needs no per-score multiply.
// ---------------------------------------------------------------------------
template<int CMODE, int BM>
__global__ __launch_bounds__(256)
void gemm_mfma(const bf16* __restrict__ Av, const bf16* __restrict__ Btp,
               const bf16* __restrict__ Av2, const bf16* __restrict__ Bt2,
               void* __restrict__ Cv, void* __restrict__ Cv2,
               void* __restrict__ Cv3,
               const float* __restrict__ emb, int Kn, int lda, int ldb, int ldc)
{
  constexpr int MI  = BM/32;         // 16-row tiles per wave
  constexpr int ITA = BM/32;         // A GLDS staging calls
  __shared__ bf16 As[(size_t)BM*64];
  __shared__ bf16 Bs[128*64];

  const int tid  = threadIdx.x;
  const int lane = tid & 63;
  const int w    = tid >> 6;
  const int col  = lane & 15, quad = lane >> 4;
  const int wr   = w >> 1, wc = w & 1;
  const size_t m0 = (size_t)blockIdx.y * BM;
  const size_t n0 = (size_t)blockIdx.x * 128;

  const bf16* Abase = Av;
  const bf16* Bt    = Btp;
  size_t nrow0 = n0;
  if constexpr (CMODE == 6) {
    if ((int)n0 >= 2304) { Abase = Av2; Bt = Bt2; nrow0 = n0 - 2304; }
  }

  const bf16* bg[4];
  #pragma unroll
  for (int it = 0; it < 4; it++) {
    int c = tid + it*256, row = c >> 3, seg = c & 7;
    bg[it] = Bt + (nrow0 + row)*ldb + (size_t)((seg ^ (row & 7))*8);
  }
  const bf16* ag[ITA];
  #pragma unroll
  for (int it = 0; it < ITA; it++) {
    int c = tid + it*256, row = c >> 3, seg = c & 7;
    ag[it] = Abase + (m0 + row)*lda + (size_t)((seg ^ (row & 7))*8);
  }

  float4v acc[MI][4];
  #pragma unroll
  for (int i=0;i<MI;i++)
    #pragma unroll
    for (int j=0;j<4;j++) acc[i][j] = (float4v){0.f,0.f,0.f,0.f};

  for (int k0 = 0; k0 < Kn; k0 += 64) {
    #pragma unroll
    for (int it = 0; it < 4; it++)
      GLDS16(bg[it] + k0, Bs + (size_t)(tid + it*256)*8);
    #pragma unroll
    for (int it = 0; it < ITA; it++)
      GLDS16(ag[it] + k0, As + (size_t)(tid + it*256)*8);
    __syncthreads();

    short8 af[MI][2], bfr[4][2];
    #pragma unroll
    for (int i=0;i<MI;i++) {
      const int ar = wr*(BM/2) + i*16 + col;
      #pragma unroll
      for (int k2=0;k2<2;k2++)
        af[i][k2] = *(const short8*)&As[ar*64 + ((k2*4+quad)^(ar&7))*8];
    }
    #pragma unroll
    for (int j=0;j<4;j++) {
      const int br = wc*64 + j*16 + col;
      #pragma unroll
      for (int k2=0;k2<2;k2++)
        bfr[j][k2] = *(const short8*)&Bs[br*64 + ((k2*4+quad)^(br&7))*8];
    }

    #pragma unroll
    for (int k2=0;k2<2;k2++)
      #pragma unroll
      for (int i=0;i<MI;i++)
        #pragma unroll
        for (int j=0;j<4;j++)
          acc[i][j] = __builtin_amdgcn_mfma_f32_16x16x32_bf16(af[i][k2], bfr[j][k2], acc[i][j], 0,0,0);
    __syncthreads();
  }

  // ---- epilogues ----
  if constexpr (CMODE == 0) {
    #pragma unroll
    for (int i=0;i<MI;i++) {
      const size_t row0 = m0 + wr*(BM/2) + i*16 + quad*4;
      #pragma unroll
      for (int j=0;j<4;j++) {
        const int c = (int)n0 + wc*64 + j*16 + col;
        #pragma unroll
        for (int r=0;r<4;r++)
          ((float*)Cv)[(row0+r)*ldc + c] = acc[i][j][r];
      }
    }
    return;
  }

  if constexpr (CMODE == 5) {
    if ((int)n0 < 384) {
      #pragma unroll
      for (int i=0;i<MI;i++) {
        const size_t row0 = m0 + wr*(BM/2) + i*16 + quad*4;
        #pragma unroll
        for (int j=0;j<4;j++) {
          const int c = (int)n0 + wc*64 + j*16 + col;
          #pragma unroll
          for (int r=0;r<4;r++)
            ((bf16*)Cv)[(row0+r)*384 + c] = __float2bfloat16(acc[i][j][r]);
        }
      }
    } else {
      // rope -> Kf dims 64..127 (unscaled); pair (j, j+2) is lane-local
      const int hh = (((int)n0 - 384) >> 6) + wc;
      #pragma unroll
      for (int i=0;i<MI;i++) {
        const size_t row0 = m0 + wr*(BM/2) + i*16 + quad*4;
        #pragma unroll
        for (int j=0;j<2;j++) {
          const int idim = j*16 + col;
          #pragma unroll
          for (int r=0;r<4;r++) {
            const size_t row = row0 + r;
            const int s = (int)(row & (S_-1));
            const float sn = emb[(size_t)s*ROT_ + idim];
            const float cs = emb[(size_t)s*ROT_ + 32 + idim];
            const float x1 = acc[i][j][r], x2 = acc[i][j+2][r];
            bf16* dst = (bf16*)Cv2 + (row*H_ + hh)*HD_ + 64 + idim;
            dst[0]  = __float2bfloat16(x1*cs - x2*sn);
            dst[32] = __float2bfloat16(x1*sn + x2*cs);
          }
        }
      }
    }
    return;
  }

  // CMODE == 6
  if ((int)n0 < 768) {
    // k_c head-split into Kf dims 0..63 (unscaled)
    #pragma unroll
    for (int i=0;i<MI;i++) {
      const size_t row0 = m0 + wr*(BM/2) + i*16 + quad*4;
      #pragma unroll
      for (int j=0;j<4;j++) {
        const int c = (int)n0 + wc*64 + j*16 + col;
        #pragma unroll
        for (int r=0;r<4;r++)
          ((bf16*)Cv)[(row0+r)*HID_ + (c>>6)*HD_ + (c&63)] = __float2bfloat16(acc[i][j][r]);
      }
    }
  } else if ((int)n0 < 2304) {
    // V transposed into Vtg[b][h][d][s]; 4 rows s-contiguous -> short4
    #pragma unroll
    for (int i=0;i<MI;i++) {
      const size_t row0 = m0 + wr*(BM/2) + i*16 + quad*4;
      const int bb = (int)(row0 >> 11), s = (int)(row0 & (S_-1));
      #pragma unroll
      for (int j=0;j<4;j++) {
        const int cv = (int)n0 - 768 + wc*64 + j*16 + col;
        const int hh = cv >> 7, d = cv & 127;
        short4v st;
        #pragma unroll
        for (int r=0;r<4;r++) st[r] = (short)f2bf(acc[i][j][r]);
        *(short4v*)((unsigned short*)Cv2 +
            ((size_t)(bb*H_+hh)*HD_ + d)*S_ + s) = st;
      }
    }
  } else if ((int)n0 < 3072) {
    // q_c head-split into Qf dims 0..63, PRE-SCALED by SC2F
    #pragma unroll
    for (int i=0;i<MI;i++) {
      const size_t row0 = m0 + wr*(BM/2) + i*16 + quad*4;
      #pragma unroll
      for (int j=0;j<4;j++) {
        const int c = (int)n0 - 2304 + wc*64 + j*16 + col;
        #pragma unroll
        for (int r=0;r<4;r++)
          ((bf16*)Cv3)[(row0+r)*HID_ + (c>>6)*HD_ + (c&63)] =
              __float2bfloat16(acc[i][j][r] * SC2F);
      }
    }
  } else {
    // rope -> Qf dims 64..127, PRE-SCALED by SC2F
    const int hh = (((int)n0 - 3072) >> 6) + wc;
    #pragma unroll
    for (int i=0;i<MI;i++) {
      const size_t row0 = m0 + wr*(BM/2) + i*16 + quad*4;
      #pragma unroll
      for (int j=0;j<2;j++) {
        const int idim = j*16 + col;
        #pragma unroll
        for (int r=0;r<4;r++) {
          const size_t row = row0 + r;
          const int s = (int)(row & (S_-1));
          const float sn = emb[(size_t)s*ROT_ + idim];
          const float cs = emb[(size_t)s*ROT_ + 32 + idim];
          const float x1 = acc[i][j][r], x2 = acc[i][j+2][r];
          bf16* dst = (bf16*)Cv3 + (row*H_ + hh)*HD_ + 64 + idim;
          dst[0]  = __float2bfloat16((x1*cs - x2*sn) * SC2F);
          dst[32] = __float2bfloat16((x1*sn + x2*cs) * SC2F);
        }
      }
    }
  }
}

// ---------------------------------------------------------------------------
// MFMA flash attention, causal. 4 waves = 64 queries/tile; 64-key blocks.
// R4 static qt-major long-first map (same-bh tiles 24 apart -> same XCD ->
// L2-resident K/V), LDS-staged K/V with T14 reg prefetch.
// VALU diet (R9, measured −7us): Q pre-scaled; native v_exp_f32; tree
// reductions.  Swapped QK^T, bulk/diag split, defer-max (T13), T5 setprio.
// ---------------------------------------------------------------------------
#define KSTR 136   // 128+8  (272B rows, 16B aligned)
#define VSTR 72    // 64+8   (144B rows, 16B aligned)
#define PSTR 72

__global__ __launch_bounds__(256)
void attn_mfma(const bf16* __restrict__ Qf, const bf16* __restrict__ Kf,
               const bf16* __restrict__ Vtg, bf16* __restrict__ at)
{
  const int rank = (int)blockIdx.x;
  const int qt = (S_/64 - 1) - rank/24;       // long-first, qt-major
  const int bh = rank % 24;
  const int h  = bh % H_, b = bh / H_;

  const int tid  = threadIdx.x;
  const int w    = tid >> 6;
  const int lane = tid & 63;
  const int col  = lane & 15;
  const int quad = lane >> 4;

  __shared__ unsigned short Ks[64*KSTR];       // 17408 B
  __shared__ unsigned short Vt[128*VSTR];      // 18432 B
  __shared__ unsigned short Ps[4][16*PSTR];    //  9216 B

  const int q0w = qt*64 + w*16;

  const unsigned short* Kb = (const unsigned short*)Kf +
      ((size_t)b*S_*H_ + h)*HD_;
  const unsigned short* Vb = (const unsigned short*)Vtg +
      (size_t)(b*H_ + h)*HD_*S_;

  const unsigned short* kgp[4]; unsigned short* kdst[4];
  const unsigned short* vgp[4]; unsigned short* vdst[4];
  #pragma unroll
  for (int it = 0; it < 4; it++) {
    int c = tid + it*256;
    int key = c >> 4, doff = (c & 15)*8;
    kgp[it]  = Kb + (size_t)key*HID_ + doff;
    kdst[it] = &Ks[key*KSTR + doff];
    int d = c >> 3, kg = (c & 7)*8;
    vgp[it]  = Vb + (size_t)d*S_ + kg;
    vdst[it] = &Vt[d*VSTR + kg];
  }

  // Q fragments (B-operand of swapped QK^T; pre-scaled by SC2F at pack)
  short8 qf[4];
  {
    const unsigned short* qrow = (const unsigned short*)Qf +
        ((size_t)((size_t)b*S_ + q0w + col)*H_ + h)*HD_;
    #pragma unroll
    for (int kk = 0; kk < 4; kk++)
      qf[kk] = *(const short8*)(qrow + kk*32 + quad*8);
  }

  float4v O[8];
  #pragma unroll
  for (int t=0;t<8;t++) O[t] = (float4v){0.f,0.f,0.f,0.f};
  float m_ln = -1e30f, l_ln = 0.f;

  short8 kr[4], vr[4];
  #pragma unroll
  for (int it = 0; it < 4; it++) {
    kr[it] = *(const short8*)kgp[it];
    vr[it] = *(const short8*)vgp[it];
  }

  for (int kb = 0; kb <= qt; kb++) {
    const int k0 = kb * 64;
    const bool diag = (kb == qt);

    #pragma unroll
    for (int it = 0; it < 4; it++) *(short8*)kdst[it] = kr[it];
    #pragma unroll
    for (int it = 0; it < 4; it++) *(short8*)vdst[it] = vr[it];
    __syncthreads();

    if (!diag) {   // T14 prefetch
      const size_t kn = (size_t)(k0 + 64);
      #pragma unroll
      for (int it = 0; it < 4; it++) {
        kr[it] = *(const short8*)(kgp[it] + kn*HID_);
        vr[it] = *(const short8*)(vgp[it] + kn);
      }
    }

    float4v Sf[4];
    #pragma unroll
    for (int tc=0;tc<4;tc++) Sf[tc] = (float4v){0.f,0.f,0.f,0.f};
    __builtin_amdgcn_s_setprio(1);
    if (!diag) {
      #pragma unroll
      for (int tc = 0; tc < 4; tc++)
        #pragma unroll
        for (int kk = 0; kk < 4; kk++) {
          short8 kfrag = *(const short8*)&Ks[(16*tc+col)*KSTR + 32*kk + quad*8];
          Sf[tc] = __builtin_amdgcn_mfma_f32_16x16x32_bf16(kfrag, qf[kk], Sf[tc], 0,0,0);
        }
    } else {
      #pragma unroll
      for (int tc = 0; tc < 4; tc++) {
        if (tc <= w) {
          #pragma unroll
          for (int kk = 0; kk < 4; kk++) {
            short8 kfrag = *(const short8*)&Ks[(16*tc+col)*KSTR + 32*kk + quad*8];
            Sf[tc] = __builtin_amdgcn_mfma_f32_16x16x32_bf16(kfrag, qf[kk], Sf[tc], 0,0,0);
          }
        }
      }
    }
    __builtin_amdgcn_s_setprio(0);

    // ---- softmax (log2 domain; scores already scaled via Qf) ----
    float sv[4][4];
    if (!diag) {
      #pragma unroll
      for (int tc = 0; tc < 4; tc++)
        #pragma unroll
        for (int r = 0; r < 4; r++)
          sv[tc][r] = Sf[tc][r];
    } else {
      const int qrel = w*16 + col;
      #pragma unroll
      for (int tc = 0; tc < 4; tc++)
        #pragma unroll
        for (int r = 0; r < 4; r++)
          sv[tc][r] = (tc*16 + quad*4 + r > qrel) ? -3.0e38f : Sf[tc][r];
    }
    // tree max (depth 4)
    float ma[4];
    #pragma unroll
    for (int tc = 0; tc < 4; tc++)
      ma[tc] = fmaxf(fmaxf(sv[tc][0], sv[tc][1]), fmaxf(sv[tc][2], sv[tc][3]));
    float pmax = fmaxf(fmaxf(ma[0], ma[1]), fmaxf(ma[2], ma[3]));
    pmax = fmaxf(pmax, __shfl_xor(pmax, 16));
    pmax = fmaxf(pmax, __shfl_xor(pmax, 32));

    if (__all(pmax <= m_ln + 11.0f)) {        // T13 defer-max: no rescale
      float sa[4];
      #pragma unroll
      for (int tc = 0; tc < 4; tc++) {
        #pragma unroll
        for (int r = 0; r < 4; r++)
          sv[tc][r] = __builtin_amdgcn_exp2f(sv[tc][r] - m_ln);
        sa[tc] = (sv[tc][0] + sv[tc][1]) + (sv[tc][2] + sv[tc][3]);
      }
      float lt = (sa[0] + sa[1]) + (sa[2] + sa[3]);
      lt += __shfl_xor(lt, 16);
      lt += __shfl_xor(lt, 32);
      l_ln += lt;
    } else {
      const float mnew = fmaxf(m_ln, pmax);
      float sa[4];
      #pragma unroll
      for (int tc = 0; tc < 4; tc++) {
        #pragma unroll
        for (int r = 0; r < 4; r++)
          sv[tc][r] = __builtin_amdgcn_exp2f(sv[tc][r] - mnew);
        sa[tc] = (sv[tc][0] + sv[tc][1]) + (sv[tc][2] + sv[tc][3]);
      }
      float lt = (sa[0] + sa[1]) + (sa[2] + sa[3]);
      lt += __shfl_xor(lt, 16);
      lt += __shfl_xor(lt, 32);
      const float al = __builtin_amdgcn_exp2f(m_ln - mnew);
      l_ln = l_ln * al + lt;
      m_ln = mnew;
      float alr[4];
      #pragma unroll
      for (int r = 0; r < 4; r++) alr[r] = __shfl(al, quad*4 + r);
      #pragma unroll
      for (int t = 0; t < 8; t++)
        #pragma unroll
        for (int r = 0; r < 4; r++) O[t][r] *= alr[r];
    }

    #pragma unroll
    for (int tc = 0; tc < 4; tc++) {
      short4v pw;
      pw[0] = (short)f2bf(sv[tc][0]); pw[1] = (short)f2bf(sv[tc][1]);
      pw[2] = (short)f2bf(sv[tc][2]); pw[3] = (short)f2bf(sv[tc][3]);
      *(short4v*)&Ps[w][col*PSTR + tc*16 + quad*4] = pw;
    }

    __builtin_amdgcn_s_setprio(1);
    if (!diag) {
      #pragma unroll
      for (int ks = 0; ks < 2; ks++) {
        short8 pf = *(const short8*)&Ps[w][col*PSTR + 32*ks + quad*8];
        #pragma unroll
        for (int t = 0; t < 8; t++) {
          short8 vf = *(const short8*)&Vt[(16*t + col)*VSTR + 32*ks + quad*8];
          O[t] = __builtin_amdgcn_mfma_f32_16x16x32_bf16(pf, vf, O[t], 0,0,0);
        }
      }
    } else {
      #pragma unroll
      for (int ks = 0; ks < 2; ks++) {
        if (ks == 0 || w >= 2) {
          short8 pf = *(const short8*)&Ps[w][col*PSTR + 32*ks + quad*8];
          #pragma unroll
          for (int t = 0; t < 8; t++) {
            short8 vf = *(const short8*)&Vt[(16*t + col)*VSTR + 32*ks + quad*8];
            O[t] = __builtin_amdgcn_mfma_f32_16x16x32_bf16(pf, vf, O[t], 0,0,0);
          }
        }
      }
    }
    __builtin_amdgcn_s_setprio(0);
    __syncthreads();
  }

  float lr[4];
  #pragma unroll
  for (int r = 0; r < 4; r++) lr[r] = __shfl(l_ln, quad*4 + r);
  #pragma unroll
  for (int r = 0; r < 4; r++) {
    const float linv = 1.f / lr[r];
    const size_t mq = (size_t)b*S_ + q0w + quad*4 + r;
    bf16* dst = at + mq*HID_ + h*HD_ + col;
    #pragma unroll
    for (int t = 0; t < 8; t++)
      dst[16*t] = __float2bfloat16(O[t][r] * linv);
  }
}

extern "C" void kernel_launch(void* const* d_in, const int* in_sizes, int n_in,
                              void* d_out, int out_size, void* d_ws, size_t ws_size,
                              hipStream_t stream)
{
  float* out = (float*)d_out;

  // Size guard tripwire.
  static const int sz_dict[10] = {6291456,131072,294912,294912,147456,
                                  147456,294912,1179648,147456,2359296};
  int bad = -1;
  if (n_in < 10) bad = 15;
  else {
    for (int i = 0; i < 10; i++)
      if (in_sizes[i] != sz_dict[i]) { bad = i; break; }
  }
  if (bad >= 0) {
    float v = 1.0e6f * (float)(1 + bad);
    if (bad < 10) v += (float)(in_sizes[bad] % 1000000);
    fillf_k<<<(out_size + 255)/256, 256, 0, stream>>>(out, v, out_size);
    return;
  }

  const float* hidden = (const float*)d_in[0];
  const float* emb    = (const float*)d_in[1];
  const float* Wkvd   = (const float*)d_in[2];
  const float* Wqd    = (const float*)d_in[3];
  const float* Wku    = (const float*)d_in[4];
  const float* Wqu    = (const float*)d_in[5];
  const float* Wvu    = (const float*)d_in[6];
  const float* Wrk    = (const float*)d_in[7];
  const float* Wrq    = (const float*)d_in[8];
  const float* Wo     = (const float*)d_in[9];

  // --- workspace carve (256B aligned each) ---
  char* wp = (char*)d_ws;
  size_t used = 0;
  auto alloc = [&](size_t bytes) -> void* {
    void* p = wp + used;
    used += (bytes + 255) & ~(size_t)255;
    return p;
  };
  bf16*  hb    = (bf16*)alloc((size_t)M_*HID_*2);        // hidden bf16
  bf16*  dout  = (bf16*)alloc((size_t)M_*384*2);         // [kvd|qd] (M,384)
  bf16*  Kf    = (bf16*)alloc((size_t)M_*HID_*2);        // [m][h][128] bf16
  bf16*  Qf    = (bf16*)alloc((size_t)M_*HID_*2);
  bf16*  Vtg   = (bf16*)alloc((size_t)B_*H_*HD_*S_*2);   // [b][h][d][s] bf16
  bf16*  at    = (bf16*)alloc((size_t)M_*HID_*2);
  bf16*  WdkrT = (bf16*)alloc((size_t)1152*HID_*2);      // [WkvdT;WqdT;WrkT]
  bf16*  WkvuT = (bf16*)alloc((size_t)2304*LAT_*2);      // [WkuT;WvuT]
  bf16*  WqurT = (bf16*)alloc((size_t)1536*LAT_*2);      // [WquT;WrqT]
  bf16*  WoT   = (bf16*)alloc((size_t)HID_*HID_*2);

  if (used > ws_size) {   // workspace tripwire
    fillf_k<<<(out_size + 255)/256, 256, 0, stream>>>(out, 5.0e7f, out_size);
    return;
  }

  // --- merged weight packs + packA: ONE launch ---
  packT9_k<<<dim3(48,48,9), 256, 0, stream>>>(
      Wkvd, Wqd, Wrk, Wo, Wku, Wvu, Wqu, Wrq,
      WdkrT, WdkrT + (size_t)192*HID_, WdkrT + (size_t)384*HID_, WoT,
      WkvuT, WkvuT + (size_t)768*LAT_, WqurT, WqurT + (size_t)768*LAT_,
      hidden, hb);

  // --- fused MFMA GEMMs (single-buffered) ---
  // G1: hb @ [Wkvd;Wqd;Wrk]^T -> dout | rope-K into Kf[64..127]  (576 blocks)
  gemm_mfma<5,64><<<dim3(9, M_/64), 256, 0, stream>>>(
      hb, WdkrT, nullptr, nullptr, dout, Kf, nullptr, emb, HID_, HID_, HID_, 0);
  // G23: [dout|qd] @ [Wku;Wvu | Wqu;Wrq]^T -> k_c->Kf, V->Vtg, q_c->Qf, ropeQ
  //     R12: BM=64 (1920 blocks, 24.5 KB LDS -> ~6 blocks/CU); A/B panels
  //     are XCD-L2-resident so the extra A re-reads are L2-hits.
  gemm_mfma<6,64><<<dim3(30, M_/64), 256, 0, stream>>>(
      dout, WkvuT, dout + 192, WqurT, Kf, Vtg, Qf, emb, LAT_, 384, LAT_, 0);

  // MFMA flash attention (R4 static qt-major long-first, LDS-staged)
  attn_mfma<<<NTILE_, 256, 0, stream>>>(Qf, Kf, Vtg, at);

  // G4: out = at @ Wo   (BM=64: 768 blocks for full CU coverage)
  gemm_mfma<0,64><<<dim3(12, M_/64), 256, 0, stream>>>(
      at, WoT, nullptr, nullptr, out, nullptr, nullptr, emb, HID_, HID_, HID_, HID_);
}